// Round 8
// baseline (208.120 us; speedup 1.0000x reference)
//
#include <hip/hip_runtime.h>
#include <stdint.h>

typedef __bf16 bf16;
typedef __bf16 bf16x8 __attribute__((ext_vector_type(8)));
typedef __bf16 bf16x4 __attribute__((ext_vector_type(4)));
typedef _Float16 f16;
typedef f16 f16x8 __attribute__((ext_vector_type(8)));
typedef f16 f16x4 __attribute__((ext_vector_type(4)));
typedef float f32x4 __attribute__((ext_vector_type(4)));

#define LQ    16384   // B*L total rows
#define CDIM  1024
#define DDIM  128
#define NSPLIT 4
#define QS 0.12751741f   // (1/sqrt(128)) * log2(e): folded into Q -> softmax uses exp2

// ---------------- K0: Wt[3][128][1024] (bf16, Q rows prescaled) + bias_all[384]
__global__ void prep_kernel(const float* __restrict__ Wq, const float* __restrict__ Wk,
                            const float* __restrict__ Wv, const float* __restrict__ bq,
                            const float* __restrict__ bk, const float* __restrict__ bv,
                            bf16* __restrict__ Wt, float* __restrict__ bias_all) {
  int idx = blockIdx.x * 256 + threadIdx.x;      // 0 .. 3*131072
  int p = idx >> 17;
  int rem = idx & 131071;
  int k = rem >> 7, n = rem & 127;
  const float* W = (p == 0) ? Wq : (p == 1) ? Wk : Wv;
  float s = (p == 0) ? QS : 1.0f;
  Wt[(size_t)(p * 128 + n) * CDIM + k] = (bf16)(W[rem] * s);
  if (idx < 384) {
    int pp = idx >> 7, nn = idx & 127;
    const float* b = (pp == 0) ? bq : (pp == 1) ? bk : bv;
    bias_all[idx] = b[nn] * ((pp == 0) ? QS : 1.0f);
  }
}

// ---------------- K1: QKV GEMM (round-4 body: 64x128 tile, grid (256,3), occ 3)
__global__ __launch_bounds__(256, 3) void qkv_gemm(
    const float* __restrict__ x, const bf16* __restrict__ Wt,
    const float* __restrict__ bias_all,
    bf16* __restrict__ Qw, bf16* __restrict__ Kw, f16* __restrict__ Vtw) {
  __shared__ bf16 Al[64 * 72];    // [m][k] pad 64->72
  __shared__ bf16 Bl[128 * 72];   // [n][k] pad
  const int t = threadIdx.x;
  const int w = t >> 6;
  const int lane = t & 63;
  const int l15 = lane & 15;
  const int quad = lane >> 4;
  const int y = blockIdx.y;
  const int m0 = blockIdx.x * 64;
  const bf16* W = Wt + (size_t)y * (DDIM * CDIM);
  const int m_off = (w & 1) * 32;
  const int n_off = (w >> 1) * 64;
  const int xr = t >> 4;          // 0..15 (+c*16)
  const int xc = (t & 15) << 2;   // x staging col (float4)
  const int wr = t >> 3;          // 0..31 (+c*32)
  const int wc = (t & 7) << 3;    // W staging col

  f32x4 zero4 = {0.f, 0.f, 0.f, 0.f};
  f32x4 acc[2][4];
#pragma unroll
  for (int i = 0; i < 2; i++)
#pragma unroll
    for (int j = 0; j < 4; j++) acc[i][j] = zero4;

  float4 xa[4];
  bf16x8 wa[4];
#pragma unroll
  for (int c = 0; c < 4; c++)
    xa[c] = *(const float4*)&x[(size_t)(m0 + c * 16 + xr) * CDIM + xc];
#pragma unroll
  for (int c = 0; c < 4; c++)
    wa[c] = *(const bf16x8*)&W[(size_t)(c * 32 + wr) * CDIM + wc];

  for (int kc = 0; kc < 16; kc++) {
    __syncthreads();
#pragma unroll
    for (int c = 0; c < 4; c++) {
      bf16x4 v;
      v[0] = (bf16)xa[c].x; v[1] = (bf16)xa[c].y;
      v[2] = (bf16)xa[c].z; v[3] = (bf16)xa[c].w;
      *(bf16x4*)&Al[(c * 16 + xr) * 72 + xc] = v;
    }
#pragma unroll
    for (int c = 0; c < 4; c++)
      *(bf16x8*)&Bl[(c * 32 + wr) * 72 + wc] = wa[c];
    __syncthreads();

    const int kn = (kc < 15 ? kc + 1 : 15) * 64;   // clamped prefetch
#pragma unroll
    for (int c = 0; c < 4; c++)
      xa[c] = *(const float4*)&x[(size_t)(m0 + c * 16 + xr) * CDIM + kn + xc];
#pragma unroll
    for (int c = 0; c < 4; c++)
      wa[c] = *(const bf16x8*)&W[(size_t)(c * 32 + wr) * CDIM + kn + wc];

#pragma unroll
    for (int ks = 0; ks < 2; ks++) {
      bf16x8 af[2], bfr[4];
#pragma unroll
      for (int mt = 0; mt < 2; mt++)
        af[mt] = *(const bf16x8*)&Al[(m_off + mt * 16 + l15) * 72 + ks * 32 + quad * 8];
#pragma unroll
      for (int nt = 0; nt < 4; nt++)
        bfr[nt] = *(const bf16x8*)&Bl[(n_off + nt * 16 + l15) * 72 + ks * 32 + quad * 8];
#pragma unroll
      for (int mt = 0; mt < 2; mt++)
#pragma unroll
        for (int nt = 0; nt < 4; nt++)
          acc[mt][nt] = __builtin_amdgcn_mfma_f32_16x16x32_bf16(af[mt], bfr[nt], acc[mt][nt], 0, 0, 0);
    }
  }

  float bias4[4];
#pragma unroll
  for (int nt = 0; nt < 4; nt++) bias4[nt] = bias_all[y * 128 + n_off + nt * 16 + l15];

  if (y < 2) {
    bf16* outp = (y == 0) ? Qw : Kw;
#pragma unroll
    for (int mt = 0; mt < 2; mt++)
#pragma unroll
      for (int nt = 0; nt < 4; nt++) {
        int n = n_off + nt * 16 + l15;
#pragma unroll
        for (int r = 0; r < 4; r++) {
          int m = m0 + m_off + mt * 16 + quad * 4 + r;
          outp[(size_t)m * DDIM + n] = (bf16)(acc[mt][nt][r] + bias4[nt]);
        }
      }
  } else {
#pragma unroll
    for (int mt = 0; mt < 2; mt++)
#pragma unroll
      for (int nt = 0; nt < 4; nt++) {
        int n = n_off + nt * 16 + l15;
        int m = m0 + m_off + mt * 16 + quad * 4;   // 4 consecutive q rows
        f16x4 pv;
#pragma unroll
        for (int r = 0; r < 4; r++) pv[r] = (f16)(acc[mt][nt][r] + bias4[nt]);
        *(f16x4*)&Vtw[(size_t)n * LQ + m] = pv;
      }
  }
}

// ---------------- K2: flash attention ----------------------------------
// grid (128 q-blocks of 128 rows, 4 KV quarters), 256 thr (4 waves x 32 q rows).
// K-frags straight from GLOBAL (L1-shared, no barrier dependence); only V
// staged in LDS (double-buffered, 1 barrier/tile). s-major strip loop.
__global__ __launch_bounds__(256, 2) void flash_kernel(
    const bf16* __restrict__ Qw, const bf16* __restrict__ Kw, const f16* __restrict__ Vtw,
    f16* __restrict__ Opb, float* __restrict__ lp) {
  __shared__ f16 Vl[2][128 * 72];    // [d][kv] pad 64->72 (36 KB total)

  const int t = threadIdx.x;
  const int w = t >> 6;
  const int lane = t & 63;
  const int l15 = lane & 15;
  const int quad = lane >> 4;
  const int qb = blockIdx.x;          // 0..127
  const int sp = blockIdx.y;          // 0..3
  const int batch = qb >> 5;
  const int q0w = qb * 128 + w * 32;
  const int kv_base = batch * 4096 + sp * 1024;

  // Q fragments (B-operand of S^T): B[k=d][n=q]
  bf16x8 qf[2][4];
#pragma unroll
  for (int nq = 0; nq < 2; nq++)
#pragma unroll
    for (int ks = 0; ks < 4; ks++)
      qf[nq][ks] = *(const bf16x8*)&Qw[(size_t)(q0w + nq * 16 + l15) * DDIM + ks * 32 + quad * 8];

  f32x4 zero4 = {0.f, 0.f, 0.f, 0.f};
  f32x4 o[2][8];                      // O rows q=nq*16+quad*4+r, cols d=dt*16+l15
#pragma unroll
  for (int nq = 0; nq < 2; nq++)
#pragma unroll
    for (int dt = 0; dt < 8; dt++) o[nq][dt] = zero4;
  f32x4 li4[2];                       // row sums
  li4[0] = zero4; li4[1] = zero4;

  f16x4 onef = {(f16)1.f, (f16)1.f, (f16)1.f, (f16)1.f};

  const int vr = t >> 3;              // 0..31 (+c*32)
  const int vcol = (t & 7) << 3;

  f16x8 va[4];
#pragma unroll
  for (int c = 0; c < 4; c++)
    va[c] = *(const f16x8*)&Vtw[(size_t)(c * 32 + vr) * LQ + kv_base + vcol];

  for (int tile = 0; tile < 16; tile++) {
    const int kv0 = kv_base + tile * 64;
    f16* Vb = Vl[tile & 1];
#pragma unroll
    for (int c = 0; c < 4; c++)
      *(f16x8*)&Vb[(c * 32 + vr) * 72 + vcol] = va[c];

    const int kvn = kv_base + (tile < 15 ? tile + 1 : 15) * 64;  // clamped prefetch
#pragma unroll
    for (int c = 0; c < 4; c++)
      va[c] = *(const f16x8*)&Vtw[(size_t)(c * 32 + vr) * LQ + kvn + vcol];

    __syncthreads();   // V staging visible; prev-buf reads done (1 barrier/tile)

    // s-major strips of 16 kv: K from global, S^T = K·Q^T, exp2, PV from regs
#pragma unroll
    for (int s = 0; s < 4; s++) {
      bf16x8 kf[4];
#pragma unroll
      for (int ks = 0; ks < 4; ks++)
        kf[ks] = *(const bf16x8*)&Kw[(size_t)(kv0 + s * 16 + l15) * DDIM + ks * 32 + quad * 8];

      f32x4 sv[2];
      sv[0] = zero4; sv[1] = zero4;
#pragma unroll
      for (int ks = 0; ks < 4; ks++)
#pragma unroll
        for (int nq = 0; nq < 2; nq++)
          sv[nq] = __builtin_amdgcn_mfma_f32_16x16x32_bf16(kf[ks], qf[nq][ks], sv[nq], 0, 0, 0);

      f16x4 pa[2];
#pragma unroll
      for (int nq = 0; nq < 2; nq++) {
        f16x4 p;
#pragma unroll
        for (int r = 0; r < 4; r++) p[r] = (f16)exp2f(sv[nq][r]);
        pa[nq] = p;
      }

#pragma unroll
      for (int dt = 0; dt < 8; dt++) {
        f16x4 vf = *(const f16x4*)&Vb[(dt * 16 + l15) * 72 + s * 16 + quad * 4];
#pragma unroll
        for (int nq = 0; nq < 2; nq++)
          o[nq][dt] = __builtin_amdgcn_mfma_f32_16x16x16f16(pa[nq], vf, o[nq][dt], 0, 0, 0);
      }
#pragma unroll
      for (int nq = 0; nq < 2; nq++)
        li4[nq] = __builtin_amdgcn_mfma_f32_16x16x16f16(pa[nq], onef, li4[nq], 0, 0, 0);
    }
  }

  // epilogue: unnormalized O (f16) + row sums l
  const size_t po = (size_t)sp * LQ * DDIM;
#pragma unroll
  for (int nq = 0; nq < 2; nq++)
#pragma unroll
    for (int dt = 0; dt < 8; dt++)
#pragma unroll
      for (int r = 0; r < 4; r++)
        Opb[po + (size_t)(q0w + nq * 16 + quad * 4 + r) * DDIM + dt * 16 + l15] = (f16)o[nq][dt][r];
  if (l15 == 0) {
#pragma unroll
    for (int nq = 0; nq < 2; nq++)
#pragma unroll
      for (int r = 0; r < 4; r++)
        lp[(size_t)sp * LQ + q0w + nq * 16 + quad * 4 + r] = li4[nq][r];
  }
}

// ---------------- K3: combine: out = (sum O_sp) / (sum l_sp) ----------------
__global__ void combine_kernel(const f16* __restrict__ Opb, const float* __restrict__ lp,
                               float* __restrict__ out) {
  int idx = blockIdx.x * 256 + threadIdx.x;   // LQ * 32
  int q = idx >> 5;
  int d = (idx & 31) * 4;
  float lsum = 0.f;
  float acc[4] = {0.f, 0.f, 0.f, 0.f};
#pragma unroll
  for (int sp = 0; sp < NSPLIT; sp++) {
    lsum += lp[(size_t)sp * LQ + q];
    f16x4 ov = *(const f16x4*)&Opb[(size_t)sp * LQ * DDIM + (size_t)q * DDIM + d];
#pragma unroll
    for (int j = 0; j < 4; j++) acc[j] += (float)ov[j];
  }
  float inv = 1.0f / lsum;
  float4 r;
  r.x = acc[0] * inv; r.y = acc[1] * inv; r.z = acc[2] * inv; r.w = acc[3] * inv;
  *(float4*)&out[(size_t)q * DDIM + d] = r;
}

extern "C" void kernel_launch(void* const* d_in, const int* in_sizes, int n_in,
                              void* d_out, int out_size, void* d_ws, size_t ws_size,
                              hipStream_t stream) {
  const float* x  = (const float*)d_in[0];
  const float* Wq = (const float*)d_in[1];
  const float* bq = (const float*)d_in[2];
  const float* Wk = (const float*)d_in[3];
  const float* bk = (const float*)d_in[4];
  const float* Wv = (const float*)d_in[5];
  const float* bv = (const float*)d_in[6];
  char* ws = (char*)d_ws;
  bf16* Qw   = (bf16*)(ws);                              // 4 MB (prescaled by QS)
  bf16* Kw   = (bf16*)(ws + ((size_t)4 << 20));          // 4 MB
  f16*  Vtw  = (f16*)(ws + ((size_t)8 << 20));           // 4 MB (transposed [d][q], f16)
  bf16* Wt   = (bf16*)(ws + ((size_t)12 << 20));         // 768 KB
  float* bias_all = (float*)(ws + ((size_t)12 << 20) + 786432); // 1.5 KB
  f16*  Opb  = (f16*)(ws + ((size_t)13 << 20));          // 16 MB (4 splits, f16)
  float* lpp = (float*)(ws + ((size_t)29 << 20));        // 256 KB
  float* out = (float*)d_out;

  prep_kernel<<<1536, 256, 0, stream>>>(Wq, Wk, Wv, bq, bk, bv, Wt, bias_all);
  qkv_gemm<<<dim3(256, 3), 256, 0, stream>>>(x, Wt, bias_all, Qw, Kw, Vtw);
  flash_kernel<<<dim3(128, NSPLIT), 256, 0, stream>>>(Qw, Kw, Vtw, Opb, lpp);
  combine_kernel<<<2048, 256, 0, stream>>>(Opb, lpp, out);
}